// Round 5
// baseline (284.208 us; speedup 1.0000x reference)
//
#include <hip/hip_runtime.h>
#include <hip/hip_fp16.h>

// ---------------------------------------------------------------------------
// 3-layer GCN + linear head.  N=50000, E=800000, D=128.
// v5 = v3 structure (best: 277.9us) + two targeted fixes:
//  * build edge pass: 4 independent u64 atomics in flight per thread
//    (2048 edges/block) — the 43us build was atomic-RETURN-latency bound
//    (MfmaUtil 1.3%, VALU 4%).
//  * k_dinv removed: fill computes dinv from packed wsum; agg reads packed
//    cnt8 line and rsqrt's inline.  9 dispatches (was 10+memset).
// [v2 lesson: agg is LATENCY-bound; never trade bytes-per-load/MLP for
//  cache locality.  v4 lesson: agg+gemm fusion costs occupancy (LDS) and
//  balance (coarse blocks) — exactly cancels the round-trip saving.]
// ---------------------------------------------------------------------------

#define D 128
#define CNT64_STRIDE 8    // one u64 counter per 64 B cache line
#define SLOTS 64          // fixed CSR capacity per node (P(deg>=64) ~ 1e-13)

typedef __attribute__((ext_vector_type(8))) _Float16 half8;
typedef __attribute__((ext_vector_type(4))) float floatx4;

// ---- MFMA GEMM body: C = A @ W (+bias), fp16 in/out, fp32 accum ----------
// 128 rows/block, 8 waves x 16 rows, v_mfma_f32_16x16x32_f16.
// Layouts (m89/m91): A[m=lane&15][k=quad*8+j], B[k][n=lane&15] from LDS
// (W transposed, pad->136), C/D col=lane&15, row=quad*4+reg.
template <bool A_IS_F32>
__device__ __forceinline__ void gemm_body(int bid, const void* Aptr,
                                          const float* W, const float* bias,
                                          float* C32, __half* C16, int N) {
    __shared__ _Float16 Wl[128][136];
    int tid = threadIdx.x;

#pragma unroll
    for (int j = 0; j < 32; j++) {
        int e = tid + j * 512;          // 16384 elements
        Wl[e & 127][e >> 7] = (_Float16)W[e];
    }
    __syncthreads();

    int wave = tid >> 6, lane = tid & 63;
    int m = lane & 15, q = lane >> 4;
    int R0 = bid * 128 + wave * 16;

    const float*  A32p = (const float*)Aptr;
    const __half* A16p = (const __half*)Aptr;

    floatx4 acc[8];
#pragma unroll
    for (int ct = 0; ct < 8; ct++) acc[ct] = (floatx4){0.f, 0.f, 0.f, 0.f};

    int arow = R0 + m;
    bool rok = arow < N;

#pragma unroll
    for (int kk = 0; kk < 4; kk++) {
        half8 a = {0, 0, 0, 0, 0, 0, 0, 0};
        if (rok) {
            if (A_IS_F32) {
                const float* p = &A32p[(size_t)arow * 128 + kk * 32 + q * 8];
                float4 f0 = *(const float4*)p;
                float4 f1 = *(const float4*)(p + 4);
                a[0] = (_Float16)f0.x; a[1] = (_Float16)f0.y;
                a[2] = (_Float16)f0.z; a[3] = (_Float16)f0.w;
                a[4] = (_Float16)f1.x; a[5] = (_Float16)f1.y;
                a[6] = (_Float16)f1.z; a[7] = (_Float16)f1.w;
            } else {
                a = *(const half8*)&A16p[(size_t)arow * 128 + kk * 32 + q * 8];
            }
        }
#pragma unroll
        for (int ct = 0; ct < 8; ct++) {
            half8 b = *(const half8*)&Wl[ct * 16 + m][kk * 32 + q * 8];
            acc[ct] = __builtin_amdgcn_mfma_f32_16x16x32_f16(a, b, acc[ct], 0, 0, 0);
        }
    }

#pragma unroll
    for (int r = 0; r < 4; r++) {
        int row = R0 + q * 4 + r;
        if (row >= N) continue;
#pragma unroll
        for (int ct = 0; ct < 8; ct++) {
            int col = ct * 16 + m;
            float v = acc[ct][r];
            if (C16) C16[(size_t)row * 128 + col] = __float2half_rn(v);
            if (C32) C32[(size_t)row * 128 + col] = v + bias[col];
        }
    }
}

template <bool A_IS_F32>
__global__ __launch_bounds__(512) void k_gemm_mfma(const void* __restrict__ Aptr,
                                                   const float* __restrict__ W,
                                                   const float* __restrict__ bias,
                                                   float* __restrict__ C32,
                                                   __half* __restrict__ C16, int N) {
    gemm_body<A_IS_F32>(blockIdx.x, Aptr, W, bias, C32, C16, N);
}

// ---- fused: blocks [0,gg) = GEMM1 (x@W1 -> y16); [ggp,..) = edge atomics --
// Edge blocks: 2048 edges each, 4 per thread -> 4 u64 atomics IN FLIGHT
// (the atomic return latency was the 43us bottleneck at 1/thread).
__global__ __launch_bounds__(512) void k_build_gemm1(const float* __restrict__ x,
                                                     const float* __restrict__ W1,
                                                     __half* __restrict__ y16,
                                                     const int* __restrict__ dst,
                                                     const float* __restrict__ w,
                                                     unsigned long long* __restrict__ cnt8,
                                                     int* __restrict__ loc,
                                                     int N, int E, int gg, int ggp) {
    int b = (int)blockIdx.x;
    if (b < gg) {
        gemm_body<true>(b, x, W1, nullptr, nullptr, y16, N);
        return;
    }
    if (b < ggp) return;
    int base = (b - ggp) * 2048 + threadIdx.x;

    int e[4]; bool ok[4]; int d[4]; float wv[4];
#pragma unroll
    for (int k = 0; k < 4; k++) {
        e[k] = base + k * 512;
        ok[k] = e[k] < E;
        int ec = ok[k] ? e[k] : 0;
        d[k] = dst[ec];
        wv[k] = w[ec];
    }
    unsigned long long old[4];
#pragma unroll
    for (int k = 0; k < 4; k++) {
        if (ok[k]) {
            unsigned int wq = __float2uint_rn(wv[k] * 32767.0f);
            old[k] = atomicAdd(&cnt8[(size_t)d[k] * CNT64_STRIDE],
                               (1ull << 32) | (unsigned long long)wq);
        }
    }
#pragma unroll
    for (int k = 0; k < 4; k++)
        if (ok[k]) loc[e[k]] = (int)(old[k] >> 32);
}

// ---- CSR fill (fixed slots): ev[d*64+loc] = (q15 << 17) | src -------------
// dinv computed in place from the packed counters (low u32 = q15 wsum).
__global__ __launch_bounds__(256) void k_fill(const int* __restrict__ ei,
                                              const float* __restrict__ w,
                                              const unsigned int* __restrict__ wsum32,
                                              const int* __restrict__ loc,
                                              unsigned int* __restrict__ ev, int E) {
    int e = blockIdx.x * 256 + threadIdx.x;
    if (e < E) {
        int s = ei[e];
        int d = ei[E + e];
        float dvs = rsqrtf(1.0f + (float)wsum32[(size_t)s * 16] * (1.0f / 32767.0f));
        float dvd = rsqrtf(1.0f + (float)wsum32[(size_t)d * 16] * (1.0f / 32767.0f));
        float val = w[e] * dvs * dvd;   // in [0,1)
        unsigned int wq = __float2uint_rn(val * 32767.0f);
        ev[(size_t)d * SLOTS + loc[e]] = (wq << 17) | (unsigned int)s;
    }
}

// ---- aggregation: out_i = b + dinv_i^2*y_i + sum val*y_src ---------------
// One wave per node; quarter-wave (16 lanes) per edge slot; lane sl=lane&15
// covers features sl*8..sl*8+7 as one uint4 (8 fp16).  Degree-adaptive
// window (wave-uniform branch): cnt<=16 -> single 4-gather window;
// cnt>16 -> 32-slot window, 8 gathers in flight.  cnt/dinv from packed cnt8.
__device__ __forceinline__ void fma8(float acc[8], float v, uint4 q) {
    union { uint4 uu; __half2 h2[4]; } U; U.uu = q;
    float2 f0 = __half22float2(U.h2[0]);
    float2 f1 = __half22float2(U.h2[1]);
    float2 f2 = __half22float2(U.h2[2]);
    float2 f3 = __half22float2(U.h2[3]);
    acc[0] = fmaf(v, f0.x, acc[0]); acc[1] = fmaf(v, f0.y, acc[1]);
    acc[2] = fmaf(v, f1.x, acc[2]); acc[3] = fmaf(v, f1.y, acc[3]);
    acc[4] = fmaf(v, f2.x, acc[4]); acc[5] = fmaf(v, f2.y, acc[5]);
    acc[6] = fmaf(v, f3.x, acc[6]); acc[7] = fmaf(v, f3.y, acc[7]);
}

__global__ __launch_bounds__(256) void k_agg(const __half* __restrict__ y16,
                                             const unsigned long long* __restrict__ cnt8,
                                             const unsigned int* __restrict__ ev,
                                             const float* __restrict__ bias,
                                             __half* __restrict__ out16,
                                             int N, int relu) {
    int i = blockIdx.x * 4 + (threadIdx.x >> 6);
    if (i >= N) return;
    int lane = threadIdx.x & 63;
    int g = lane >> 4;
    int sl = lane & 15;

    float acc[8];
#pragma unroll
    for (int j = 0; j < 8; j++) acc[j] = 0.f;

    unsigned long long pk = cnt8[(size_t)i * CNT64_STRIDE];
    int cnt = (int)(pk >> 32);
    const unsigned int* evp = ev + (size_t)i * SLOTS;

    if (cnt > 0) {
        if (cnt <= 16) {
            // single straight-line window, 4 gathers in flight
            unsigned int p[4];
            float v[4];
            uint4 q4[4];
#pragma unroll
            for (int u = 0; u < 4; u++) {
                int idx = u * 4 + g;
                bool ok = idx < cnt;
                p[u] = evp[ok ? idx : 0];
                v[u] = ok ? (float)(p[u] >> 17) * (1.0f / 32767.0f) : 0.0f;
            }
#pragma unroll
            for (int u = 0; u < 4; u++)
                q4[u] = *(const uint4*)&y16[(size_t)(p[u] & 0x1FFFFu) * D + sl * 8];
#pragma unroll
            for (int u = 0; u < 4; u++) fma8(acc, v[u], q4[u]);
        } else {
            // 32-slot windows, 8 gathers in flight
            for (int base = 0; base < cnt; base += 32) {
                unsigned int p[8];
                float v[8];
                uint4 q4[8];
#pragma unroll
                for (int u = 0; u < 8; u++) {
                    int idx = base + u * 4 + g;
                    bool ok = idx < cnt;
                    p[u] = evp[ok ? idx : 0];
                    v[u] = ok ? (float)(p[u] >> 17) * (1.0f / 32767.0f) : 0.0f;
                }
#pragma unroll
                for (int u = 0; u < 8; u++)
                    q4[u] = *(const uint4*)&y16[(size_t)(p[u] & 0x1FFFFu) * D + sl * 8];
#pragma unroll
                for (int u = 0; u < 8; u++) fma8(acc, v[u], q4[u]);
            }
        }
    }

    // fold the 4 quarter-wave partials (lane ^16, ^32)
#pragma unroll
    for (int j = 0; j < 8; j++) {
        acc[j] += __shfl_xor(acc[j], 16, 64);
        acc[j] += __shfl_xor(acc[j], 32, 64);
    }

    if (g == 0) {
        float di = rsqrtf(1.0f + (float)(unsigned int)pk * (1.0f / 32767.0f));
        float di2 = di * di;
        union { uint4 u; __half2 h2[4]; } S;
        S.u = *(const uint4*)&y16[(size_t)i * D + sl * 8];
        float2 s0 = __half22float2(S.h2[0]);
        float2 s1 = __half22float2(S.h2[1]);
        float2 s2 = __half22float2(S.h2[2]);
        float2 s3 = __half22float2(S.h2[3]);
        float4 b0 = *(const float4*)&bias[sl * 8];
        float4 b1 = *(const float4*)&bias[sl * 8 + 4];
        float o[8];
        o[0] = b0.x + acc[0] + di2 * s0.x;
        o[1] = b0.y + acc[1] + di2 * s0.y;
        o[2] = b0.z + acc[2] + di2 * s1.x;
        o[3] = b0.w + acc[3] + di2 * s1.y;
        o[4] = b1.x + acc[4] + di2 * s2.x;
        o[5] = b1.y + acc[5] + di2 * s2.y;
        o[6] = b1.z + acc[6] + di2 * s3.x;
        o[7] = b1.w + acc[7] + di2 * s3.y;
        if (relu) {
#pragma unroll
            for (int j = 0; j < 8; j++) o[j] = fmaxf(o[j], 0.f);
        }
        union { uint4 u; __half2 h2[4]; } O;
        O.h2[0] = __float22half2_rn(make_float2(o[0], o[1]));
        O.h2[1] = __float22half2_rn(make_float2(o[2], o[3]));
        O.h2[2] = __float22half2_rn(make_float2(o[4], o[5]));
        O.h2[3] = __float22half2_rn(make_float2(o[6], o[7]));
        *(uint4*)&out16[(size_t)i * D + sl * 8] = O.u;
    }
}

// ---------------------------------------------------------------------------
extern "C" void kernel_launch(void* const* d_in, const int* in_sizes, int n_in,
                              void* d_out, int out_size, void* d_ws, size_t ws_size,
                              hipStream_t stream) {
    const float* x  = (const float*)d_in[0];
    const int*   ei = (const int*)d_in[1];     // [2,E]: src row then dst row
    const float* ew = (const float*)d_in[2];
    const float* W1 = (const float*)d_in[3];
    const float* b1 = (const float*)d_in[4];
    const float* W2 = (const float*)d_in[5];
    const float* b2 = (const float*)d_in[6];
    const float* W3 = (const float*)d_in[7];
    const float* b3 = (const float*)d_in[8];
    const float* Wl = (const float*)d_in[9];
    const float* bl = (const float*)d_in[10];

    int N = in_sizes[0] / D;    // 50000
    int E = in_sizes[2];        // 800000

    char* ws = (char*)d_ws;
    size_t off = 0;
    auto alloc = [&](size_t bytes) {
        void* p = ws + off;
        off = (off + bytes + 255) & ~(size_t)255;
        return p;
    };
    unsigned long long* cnt8 = (unsigned long long*)alloc((size_t)N * 64); // padded
    int*    loc  = (int*)alloc((size_t)E * 4);
    unsigned int* ev = (unsigned int*)alloc((size_t)N * SLOTS * 4);  // 12.8MB
    __half* yA   = (__half*)alloc((size_t)N * D * 2);   // row-major [N][128]
    __half* yB   = (__half*)alloc((size_t)N * D * 2);   // row-major [N][128]

    int nbE     = (E + 255) / 256;      // 3125 (fill)
    int nbE2048 = (E + 2047) / 2048;    // 391 (build edge part, 4 edges/thread)
    int gg      = (N + 127) / 128;      // 391 GEMM1 blocks
    int ggp     = (gg + 7) & ~7;        // 392
    int ga      = (N + 3) / 4;          // 12500 agg blocks (4 waves each)

    hipMemsetAsync(cnt8, 0, (size_t)N * 64, stream);
    k_build_gemm1<<<ggp + nbE2048, 512, 0, stream>>>(x, W1, yA, ei + E, ew,
                                                     cnt8, loc, N, E, gg, ggp);
    k_fill<<<nbE, 256, 0, stream>>>(ei, ew, (const unsigned int*)cnt8, loc, ev, E);

    k_agg<<<ga, 256, 0, stream>>>(yA, cnt8, ev, b1, yB, N, 1);
    k_gemm_mfma<false><<<gg, 512, 0, stream>>>(yB, W2, nullptr, nullptr, yA, N);
    k_agg<<<ga, 256, 0, stream>>>(yA, cnt8, ev, b2, yB, N, 1);
    k_gemm_mfma<false><<<gg, 512, 0, stream>>>(yB, W3, nullptr, nullptr, yA, N);
    k_agg<<<ga, 256, 0, stream>>>(yA, cnt8, ev, b3, yB, N, 0);
    k_gemm_mfma<false><<<gg, 512, 0, stream>>>(yB, Wl, bl, (float*)d_out, nullptr, N);
}